// Round 9
// baseline (310.057 us; speedup 1.0000x reference)
//
#include <hip/hip_runtime.h>
#include <hip/hip_bf16.h>

// B=8, N=4096, C=384, H=8, HD=48.  M = B*N = 32768.
// Pipeline (3 kernels):
//  conv_w:    Wqkv,Wproj fp32->bf16; zero accD.
//  gemm_qkv:  x(fp32, reg-staged cvt, T14-prefetched) @ Wqkv^T.
//             jobs 0-2: Q tile -> qp[tok][384] (activated bf16)
//             jobs 3-10 (head h): K+V 96-feat tile -> LDS transpose (Tt unioned
//                with As: ds-only object, NOT the glds-dest Bs — r7 lesson) ->
//                49x48 kptv/ks MFMA -> atomicAdd accD[bh][64][48]
//  attn_proj: per block = 256 tokens of one (b,h) x 128 proj cols.
//             stage qp -> attn MFMA vs accD-frags -> rcp -> A-tile (32x384) in LDS
//             -> 6-step proj K-loop (Wproj glds) -> fp32 out + bias.
//             outr buffer eliminated (-50 MB HBM, -1 launch).

typedef __attribute__((ext_vector_type(8))) short short8;
typedef __attribute__((ext_vector_type(4))) float floatx4;

#define MFMA(a, b, c) __builtin_amdgcn_mfma_f32_16x16x32_bf16((a), (b), (c), 0, 0, 0)

__device__ __forceinline__ unsigned short f2bf(float f) {
  union { float f; unsigned u; } x; x.f = f;
  unsigned r = x.u + 0x7FFFu + ((x.u >> 16) & 1u);   // RNE
  return (unsigned short)(r >> 16);
}

__device__ __forceinline__ void cv4(const float* __restrict__ in, unsigned short* __restrict__ out, int i) {
  float4 v = *(const float4*)(in + i);
  uint2 o;
  o.x = (unsigned)f2bf(v.x) | ((unsigned)f2bf(v.y) << 16);
  o.y = (unsigned)f2bf(v.z) | ((unsigned)f2bf(v.w) << 16);
  *(uint2*)(out + i) = o;
}

// ---------------- weight conversions + accD zeroing ----------------
__global__ void conv_w(const float* __restrict__ wq, const float* __restrict__ wp,
                       unsigned short* __restrict__ wqb, unsigned short* __restrict__ wpb,
                       float* __restrict__ accD) {
  const int tid = blockIdx.x * blockDim.x + threadIdx.x;
  const int stride = gridDim.x * blockDim.x * 4;
  for (int i = tid * 4; i < 442368; i += stride) cv4(wq, wqb, i);
  for (int i = tid * 4; i < 147456; i += stride) cv4(wp, wpb, i);
  float4 z = {0.f, 0.f, 0.f, 0.f};
  for (int i = tid * 4; i < 196608; i += stride) *(float4*)(accD + i) = z;
}

// ---------------- fused qkv GEMM + kptv/ks reduction ----------------
// grid = 256 M-tiles * 11 jobs, XCD-swizzled so one tile's jobs share an L2.
__global__ __launch_bounds__(256, 3) void gemm_qkv(
    const float* __restrict__ x,            // [32768][384] fp32
    const unsigned short* __restrict__ Wq,  // [1152][384] bf16
    unsigned short* __restrict__ qp,        // [32768][384] bf16 out
    float* __restrict__ accD) {             // [64][64][48] fp32
  // As (ds_write/ds_read only) unioned with Tt (live only after final K barrier).
  // Bs is a global_load_lds destination -> kept a SEPARATE object (r7: 2x slowdown).
  __shared__ union {
    unsigned short As[128 * 64];
    unsigned short Tt[2][48 * 136];
  } ua;
  __shared__ unsigned short Bs[128 * 64];

  const int cpx = gridDim.x >> 3;
  const int bid = (blockIdx.x & 7) * cpx + (blockIdx.x >> 3);
  const int mt = bid / 11;
  const int j = bid - mt * 11;
  const int tid = threadIdx.x;
  const int w = tid >> 6, lane = tid & 63;
  const int wm = w >> 1, wn = w & 1;
  const int l15 = lane & 15, l4 = lane >> 4;
  const int isQ = (j < 3);
  const int h = j - 3;

  floatx4 zero = {0.f, 0.f, 0.f, 0.f};
  floatx4 acc[4][4];
#pragma unroll
  for (int i = 0; i < 4; ++i)
#pragma unroll
    for (int jj = 0; jj < 4; ++jj) acc[i][jj] = zero;

  const size_t Abase = (size_t)mt * 128 * 384;
  const int arow = tid >> 4;            // 0..15
  const int akf = (tid & 15) * 4;       // 0..60

  // T14 prologue: prefetch x for k0=0 into regs
  float4 xv[8];
#pragma unroll
  for (int p = 0; p < 8; ++p)
    xv[p] = *(const float4*)&x[Abase + (size_t)(p * 16 + arow) * 384 + akf];

  for (int k0 = 0; k0 < 384; k0 += 64) {
    // ---- B staging first (async glds latency overlaps A cvt/ds_write) ----
    if (isQ) {
      const size_t Bb = (size_t)(j * 128) * 384;
#pragma unroll
      for (int i = 0; i < 4; ++i) {
        int li = w * 256 + i * 64 + lane;
        int row = li >> 3, col = (li & 7) << 3;
        __builtin_amdgcn_global_load_lds(
            (const __attribute__((address_space(1))) void*)(Wq + Bb + (size_t)row * 384 + k0 + col),
            (__attribute__((address_space(3))) void*)&Bs[row * 64 + col], 16, 0, 0);
      }
    } else {
#pragma unroll
      for (int i = 0; i < 3; ++i) {
        int idx = i * 256 + tid;
        int row = idx >> 3, col = (idx & 7) << 3;
        int srow = (row < 48) ? (384 + h * 48 + row) : (720 + h * 48 + row);
        __builtin_amdgcn_global_load_lds(
            (const __attribute__((address_space(1))) void*)(Wq + (size_t)srow * 384 + k0 + col),
            (__attribute__((address_space(3))) void*)&Bs[row * 64 + col], 16, 0, 0);
      }
    }
    // ---- A: cvt prefetched regs -> As ----
#pragma unroll
    for (int p = 0; p < 8; ++p) {
      int row = p * 16 + arow;
      uint2 o;
      o.x = (unsigned)f2bf(xv[p].x) | ((unsigned)f2bf(xv[p].y) << 16);
      o.y = (unsigned)f2bf(xv[p].z) | ((unsigned)f2bf(xv[p].w) << 16);
      *(uint2*)&ua.As[row * 64 + akf] = o;
    }
    __syncthreads();
    // ---- T14: issue next k-step's x loads BEFORE the MFMA phase ----
    if (k0 < 320) {
#pragma unroll
      for (int p = 0; p < 8; ++p)
        xv[p] = *(const float4*)&x[Abase + (size_t)(p * 16 + arow) * 384 + k0 + 64 + akf];
    }
    // ---- MFMA ----
#pragma unroll
    for (int kk = 0; kk < 2; ++kk) {
      short8 a[4];
#pragma unroll
      for (int mf = 0; mf < 4; ++mf)
        a[mf] = *(const short8*)&ua.As[(wm * 64 + mf * 16 + l15) * 64 + kk * 32 + l4 * 8];
      if (isQ) {
#pragma unroll
        for (int nf = 0; nf < 4; ++nf) {
          short8 b = *(const short8*)&Bs[(wn * 64 + nf * 16 + l15) * 64 + kk * 32 + l4 * 8];
#pragma unroll
          for (int mf = 0; mf < 4; ++mf) acc[mf][nf] = MFMA(a[mf], b, acc[mf][nf]);
        }
      } else {
#pragma unroll
        for (int nf = 0; nf < 3; ++nf) {
          short8 b = *(const short8*)&Bs[(wn * 48 + nf * 16 + l15) * 64 + kk * 32 + l4 * 8];
#pragma unroll
          for (int mf = 0; mf < 4; ++mf) acc[mf][nf] = MFMA(a[mf], b, acc[mf][nf]);
        }
      }
    }
    __syncthreads();
  }

  const float DN = 0.3799178430f;  // 48^-0.25
  if (isQ) {
    // Q tile -> qp[tok][384], activated
#pragma unroll
    for (int mf = 0; mf < 4; ++mf) {
#pragma unroll
      for (int nf = 0; nf < 4; ++nf) {
        int gm0 = mt * 128 + wm * 64 + mf * 16 + l4 * 4;
        int gn = j * 128 + wn * 64 + nf * 16 + l15;
#pragma unroll
        for (int r = 0; r < 4; ++r) {
          float v = fmaxf(acc[mf][nf][r] * DN, 0.f) + 1e-3f;
          qp[(size_t)(gm0 + r) * 384 + gn] = f2bf(v);
        }
      }
    }
  } else {
    // ---- transpose K (activated) / V (raw) into LDS: Tt[wn][feat][tok] ----
    // (safe: final K-loop barrier retired all As reads; Tt aliases As only)
#pragma unroll
    for (int nf = 0; nf < 3; ++nf) {
#pragma unroll
      for (int mf = 0; mf < 4; ++mf) {
        float v0 = acc[mf][nf][0], v1 = acc[mf][nf][1];
        float v2 = acc[mf][nf][2], v3 = acc[mf][nf][3];
        if (wn == 0) {
          v0 = fmaxf(v0 * DN, 0.f) + 1e-3f;
          v1 = fmaxf(v1 * DN, 0.f) + 1e-3f;
          v2 = fmaxf(v2 * DN, 0.f) + 1e-3f;
          v3 = fmaxf(v3 * DN, 0.f) + 1e-3f;
        }
        uint2 o;
        o.x = (unsigned)f2bf(v0) | ((unsigned)f2bf(v1) << 16);
        o.y = (unsigned)f2bf(v2) | ((unsigned)f2bf(v3) << 16);
        *(uint2*)&ua.Tt[wn][(nf * 16 + l15) * 136 + wm * 64 + mf * 16 + l4 * 4] = o;
      }
    }
    __syncthreads();
    // ---- second stage: out[d][m] = sum_tok V[tok][d]*Kp[tok][m]; wave3 row 0 = ks ----
    short8 ones;
    {
      unsigned short ov = (l15 == 0) ? (unsigned short)0x3F80 : (unsigned short)0;
#pragma unroll
      for (int e = 0; e < 8; ++e) ones[e] = (short)ov;
    }
    floatx4 acc2[3];
#pragma unroll
    for (int i = 0; i < 3; ++i) acc2[i] = zero;
#pragma unroll
    for (int c = 0; c < 4; ++c) {
      short8 af;
      if (w < 3)
        af = *(const short8*)&ua.Tt[1][(w * 16 + l15) * 136 + c * 32 + l4 * 8];
      else
        af = ones;
#pragma unroll
      for (int mfr = 0; mfr < 3; ++mfr) {
        short8 bf8 = *(const short8*)&ua.Tt[0][(mfr * 16 + l15) * 136 + c * 32 + l4 * 8];
        acc2[mfr] = MFMA(af, bf8, acc2[mfr]);
      }
    }
    float* dst = accD + (size_t)((mt >> 5) * 8 + h) * 3072;
    if (w < 3) {
#pragma unroll
      for (int mfr = 0; mfr < 3; ++mfr)
#pragma unroll
        for (int r = 0; r < 4; ++r)
          atomicAdd(&dst[(w * 16 + l4 * 4 + r) * 48 + mfr * 16 + l15], acc2[mfr][r]);
    } else if (l4 == 0) {
#pragma unroll
      for (int mfr = 0; mfr < 3; ++mfr)
        atomicAdd(&dst[48 * 48 + mfr * 16 + l15], acc2[mfr][0]);
    }
  }
}

// ---------------- fused attn readout + proj GEMM ----------------
// block = 256 tokens of one (b,h) x 128 proj output cols.
// grid = 1024 bm * 3 bn, XCD-swizzled (bn-triples of one bm share an XCD L2).
__global__ __launch_bounds__(256, 3) void attn_proj(
    const unsigned short* __restrict__ qp,   // [32768][384] activated Q
    const float* __restrict__ accD,          // [64][64][48]
    const unsigned short* __restrict__ Wp,   // [384][384] bf16
    const float* __restrict__ bias,          // [384]
    float* __restrict__ Cout) {              // [32768][384] fp32
  // Qs (qp staging) and Af (generated proj A-tile) are disjoint in time.
  __shared__ union {
    unsigned short Qs[256 * 52 + 64];  // 256 tok x 48 feat, stride 52; zeroed pads
    unsigned short Af[32 * 392];       // 32 scrambled rows x 384 (+8 pad vs banks)
  } uq;
  __shared__ unsigned short Bs[128 * 64];  // glds destination — separate object

  const int cpx = gridDim.x >> 3;  // 384
  const int bid = (blockIdx.x & 7) * cpx + (blockIdx.x >> 3);
  const int bm = bid / 3;              // 0..1023
  const int bn = bid - bm * 3;         // 0..2
  const int b = bm >> 7;
  const int h = (bm >> 4) & 7;
  const int n0 = (bm & 15) * 256;      // first token (within batch b) of this tile
  const int bh = b * 8 + h;
  const int tid = threadIdx.x, w = tid >> 6, lane = tid & 63;
  const int l15 = lane & 15, l4 = lane >> 4;
  const size_t rb = (size_t)b * 4096;

  // ---- B-fragments for attn: row d (0..47 kptv, 48 ks, 49..63 zeros) ----
  short8 bfr[2][4];
#pragma unroll
  for (int kk = 0; kk < 2; ++kk) {
#pragma unroll
    for (int nf = 0; nf < 4; ++nf) {
      int row = nf * 16 + l15;
      int c0 = kk * 32 + l4 * 8;
      short8 f;
      if (kk == 1 && l4 >= 2) {
#pragma unroll
        for (int e = 0; e < 8; ++e) f[e] = 0;
      } else {
        const float* p = accD + (size_t)bh * 3072 + row * 48 + c0;
        float4 v0 = *(const float4*)p;
        float4 v1 = *(const float4*)(p + 4);
        f[0] = (short)f2bf(v0.x); f[1] = (short)f2bf(v0.y);
        f[2] = (short)f2bf(v0.z); f[3] = (short)f2bf(v0.w);
        f[4] = (short)f2bf(v1.x); f[5] = (short)f2bf(v1.y);
        f[6] = (short)f2bf(v1.z); f[7] = (short)f2bf(v1.w);
      }
      bfr[kk][nf] = f;
    }
  }

  // ---- stage qp slice (coalesced 96B runs) ----
#pragma unroll
  for (int c = 0; c < 6; ++c) {
    int idx = c * 256 + tid;
    int row = idx / 6;
    int part = idx - row * 6;
    short8 v = *(const short8*)&qp[(rb + n0 + row) * 384 + h * 48 + part * 8];
    *(short8*)&uq.Qs[row * 52 + part * 8] = v;
  }
  *(uint2*)&uq.Qs[tid * 52 + 48] = (uint2){0u, 0u};
  if (tid < 64) uq.Qs[256 * 52 + tid] = 0;
  __syncthreads();

  // ---- attn MFMAs: 64 tokens per wave ----
  floatx4 zero = {0.f, 0.f, 0.f, 0.f};
  floatx4 acc[4][4];
#pragma unroll
  for (int i = 0; i < 4; ++i)
#pragma unroll
    for (int j = 0; j < 4; ++j) acc[i][j] = zero;

#pragma unroll
  for (int mf = 0; mf < 4; ++mf) {
#pragma unroll
    for (int kk = 0; kk < 2; ++kk) {
      short8 a = *(const short8*)&uq.Qs[(w * 64 + mf * 16 + l15) * 52 + kk * 32 + l4 * 8];
#pragma unroll
      for (int nf = 0; nf < 4; ++nf)
        acc[mf][nf] = MFMA(a, bfr[kk][nf], acc[mf][nf]);
    }
  }
  __syncthreads();  // Qs reads retired; Af may overwrite

  // ---- rcp-normalize, write A-tile into LDS (scrambled layout) ----
#pragma unroll
  for (int mf = 0; mf < 4; ++mf) {
    float inv[4];
#pragma unroll
    for (int r = 0; r < 4; ++r) {
      float den = __shfl(acc[mf][3][r], lane & 48, 64) + 1e-8f;
      inv[r] = __builtin_amdgcn_rcpf(den);
    }
#pragma unroll
    for (int nf = 0; nf < 3; ++nf) {
#pragma unroll
      for (int r = 0; r < 4; ++r) {
        int t = w * 64 + mf * 16 + l4 * 4 + r;   // token-local 0..255
        int d = nf * 16 + l15;
        uq.Af[(t >> 3) * 392 + (t & 7) * 48 + d] = f2bf(acc[mf][nf][r] * inv[r]);
      }
    }
  }

  // ---- proj K-loop: C[32 x 128] += Af[32 x 384] * Wp[bn*128.. , :]^T ----
  floatx4 accp[2][2];
#pragma unroll
  for (int i = 0; i < 2; ++i)
#pragma unroll
    for (int j = 0; j < 2; ++j) accp[i][j] = zero;

  for (int k0 = 0; k0 < 384; k0 += 64) {
#pragma unroll
    for (int i = 0; i < 4; ++i) {
      int idx = i * 256 + tid;
      int row = idx >> 3, col = (idx & 7) << 3;
      __builtin_amdgcn_global_load_lds(
          (const __attribute__((address_space(1))) void*)(Wp + (size_t)(bn * 128 + row) * 384 + k0 + col),
          (__attribute__((address_space(3))) void*)&Bs[row * 64 + col], 16, 0, 0);
    }
    __syncthreads();  // first iter: also covers Af ds_writes
#pragma unroll
    for (int kk = 0; kk < 2; ++kk) {
      short8 a[2], bfp[2];
#pragma unroll
      for (int mf = 0; mf < 2; ++mf)
        a[mf] = *(const short8*)&uq.Af[(mf * 16 + l15) * 392 + k0 + kk * 32 + l4 * 8];
#pragma unroll
      for (int nf = 0; nf < 2; ++nf)
        bfp[nf] = *(const short8*)&Bs[(w * 32 + nf * 16 + l15) * 64 + kk * 32 + l4 * 8];
#pragma unroll
      for (int mf = 0; mf < 2; ++mf)
#pragma unroll
        for (int nf = 0; nf < 2; ++nf)
          accp[mf][nf] = MFMA(a[mf], bfp[nf], accp[mf][nf]);
    }
    __syncthreads();
  }

  // ---- epilogue: fp32 + bias ----
#pragma unroll
  for (int mf = 0; mf < 2; ++mf) {
#pragma unroll
    for (int nf = 0; nf < 2; ++nf) {
      int gm0 = bm * 32 + mf * 16 + l4 * 4;
      int gn = bn * 128 + w * 32 + nf * 16 + l15;
#pragma unroll
      for (int r = 0; r < 4; ++r)
        Cout[(size_t)(gm0 + r) * 384 + gn] = accp[mf][nf][r] + bias[gn];
    }
  }
}

extern "C" void kernel_launch(void* const* d_in, const int* in_sizes, int n_in,
                              void* d_out, int out_size, void* d_ws, size_t ws_size,
                              hipStream_t stream) {
  const float* x = (const float*)d_in[0];
  const float* Wqkv = (const float*)d_in[1];
  const float* Wproj = (const float*)d_in[2];
  const float* bproj = (const float*)d_in[3];

  char* ws = (char*)d_ws;
  unsigned short* qp = (unsigned short*)(ws);                 // 25165824
  float* accD = (float*)(ws + 25165824);                      // 786432
  unsigned short* wqkvb = (unsigned short*)(ws + 25952256);   // 884736
  unsigned short* wprojb = (unsigned short*)(ws + 26836992);  // 294912
  // total ws use: 27131904 bytes

  conv_w<<<256, 256, 0, stream>>>(Wqkv, Wproj, wqkvb, wprojb, accD);
  gemm_qkv<<<2816, 256, 0, stream>>>(x, wqkvb, qp, accD);
  attn_proj<<<3072, 256, 0, stream>>>(qp, accD, wprojb, bproj, (float*)d_out);
}